// Round 2
// baseline (490.312 us; speedup 1.0000x reference)
//
#include <hip/hip_runtime.h>

// InterConv: B=2048, F=39, E=64, C=64, P = F*(F-1)/2 = 741
// out[b*(C*P) + c*P + p] = relu( x[b,ii[p]]·Wi[c] + x[b,jj[p]]·Wj[c] + bias[c] )
//
// Fused one-kernel design: block = one batch b, 256 threads.
//  phase 0: stage xT[e][f] (stride 40) and Wl[e][cw] (stride 132) into LDS,
//           build pair table, stage bias. Decode per-thread pair offsets.
//  phase 1: per-thread 5f x 4cw register-tile GEMM (K=64) -> acc in VGPRs.
//  phase 1.5: ds_write_b128 A[f][cw] (stride 132, 16B-aligned rows; aliases staging).
//  phase 2: per (p, 4-channel) slot: 2x ds_read_b128 + 4 coalesced nontemporal
//           b32 stores. Fully unrolled, high ILP, no dependent LDS chains.

#define BATCH 2048
#define FDIM  39
#define EDIM  64
#define CDIM  64
#define NPAIR 741
#define CP    (CDIM * NPAIR)   // 47424
#define XSTR  40    // xT leading-dim pad
#define WSTR  132   // Wl leading-dim pad (128+4; 16B-aligned rows, stride%32==4 -> balanced banks)
#define ASTR  132   // A[f][cw] stride, same property

__global__ __launch_bounds__(256) void interconv_fused(
    const float* __restrict__ x,     // [B, F, E]
    const float* __restrict__ Wg,    // [C, 1, 2, E] flat: c*128 + which*64 + e
    const float* __restrict__ bias,  // [C]
    float* __restrict__ out)         // [B, C*P] with layout c*P + p
{
    __shared__ float smem[EDIM * XSTR + EDIM * WSTR]; // 2560 + 8448 = 11008 floats (44032 B)
    __shared__ int   tab[NPAIR];
    __shared__ float sbias[CDIM];

    float* xT = smem;               // [EDIM][XSTR]
    float* Wl = smem + EDIM * XSTR; // [EDIM][WSTR]
    float* A  = smem;               // [40][ASTR] = 5280 floats, aliases staging (after barrier)

    const int tid = threadIdx.x;
    const int b   = blockIdx.x;
    const float* xg = x + (size_t)b * (FDIM * EDIM);

    // ---- phase 0: staging ----
    for (int q = tid; q < (FDIM * EDIM) / 4; q += 256) {
        float4 v = ((const float4*)xg)[q];
        int flat = q << 2;
        int f  = flat >> 6;
        int e0 = flat & 63;
        xT[(e0 + 0) * XSTR + f] = v.x;
        xT[(e0 + 1) * XSTR + f] = v.y;
        xT[(e0 + 2) * XSTR + f] = v.z;
        xT[(e0 + 3) * XSTR + f] = v.w;
    }
    for (int q = tid; q < (CDIM * 2 * EDIM) / 4; q += 256) {
        float4 v = ((const float4*)Wg)[q];
        int flat = q << 2;
        int c   = flat >> 7;
        int rem = flat & 127;
        int wh  = rem >> 6;
        int e0  = rem & 63;
        int cw  = (wh << 6) | c;
        Wl[(e0 + 0) * WSTR + cw] = v.x;
        Wl[(e0 + 1) * WSTR + cw] = v.y;
        Wl[(e0 + 2) * WSTR + cw] = v.z;
        Wl[(e0 + 3) * WSTR + cw] = v.w;
    }
    // pair table: p -> (i, j), i<j, row-major triu order. S(i) = i*(77-i)/2.
    for (int idx = tid; idx < NPAIR; idx += 256) {
        int i = (int)floorf((77.0f - sqrtf(5929.0f - 8.0f * (float)idx)) * 0.5f);
        i = i < 0 ? 0 : (i > FDIM - 2 ? FDIM - 2 : i);
        while ((i + 1) * (77 - (i + 1)) / 2 <= idx) ++i;
        while (i * (77 - i) / 2 > idx) --i;
        int j = idx - i * (77 - i) / 2 + i + 1;
        tab[idx] = i | (j << 8);
    }
    if (tid < CDIM) sbias[tid] = bias[tid];
    __syncthreads();

    // decode this thread's 3 pair slots into A float-offsets (registers)
    int iOff[3], jOff[3];
#pragma unroll
    for (int k = 0; k < 3; ++k) {
        int p = tid + (k << 8);
        int t = (p < NPAIR) ? tab[p] : 0;
        iOff[k] = (t & 0xff) * ASTR;         // Wi-part column block at [i][c]
        jOff[k] = (t >> 8) * ASTR + CDIM;    // Wj-part column block at [j][64+c]
    }

    // ---- phase 1: GEMM, per-thread 5f x 4cw tile ----
    const int ft  = tid >> 5;   // 0..7  -> f0 = ft*5 covers 0..39 (f=39 is pad, never read back)
    const int ct  = tid & 31;   // 0..31 -> cw0 = ct*4
    const int f0  = ft * 5;
    const int cw0 = ct << 2;

    float acc[5][4];
#pragma unroll
    for (int a = 0; a < 5; ++a)
#pragma unroll
        for (int q = 0; q < 4; ++q) acc[a][q] = 0.0f;

#pragma unroll 4
    for (int e = 0; e < EDIM; ++e) {
        float4 wv = *(const float4*)(Wl + e * WSTR + cw0);
        float xv[5];
#pragma unroll
        for (int a = 0; a < 5; ++a) xv[a] = xT[e * XSTR + f0 + a];
#pragma unroll
        for (int a = 0; a < 5; ++a) {
            acc[a][0] = fmaf(xv[a], wv.x, acc[a][0]);
            acc[a][1] = fmaf(xv[a], wv.y, acc[a][1]);
            acc[a][2] = fmaf(xv[a], wv.z, acc[a][2]);
            acc[a][3] = fmaf(xv[a], wv.w, acc[a][3]);
        }
    }
    __syncthreads();  // all reads of xT/Wl done before aliasing writes

    // ---- phase 1.5: write A[f][cw] with b128 stores ----
#pragma unroll
    for (int a = 0; a < 5; ++a) {
        float4 v = make_float4(acc[a][0], acc[a][1], acc[a][2], acc[a][3]);
        *(float4*)(A + (f0 + a) * ASTR + cw0) = v;
    }
    __syncthreads();

    // ---- phase 2: gather + bias + relu + coalesced nontemporal stores ----
    float* outb = out + (size_t)b * CP;
#pragma unroll
    for (int k = 0; k < 3; ++k) {
        if (k == 2 && tid >= NPAIR - 512) continue;   // 741 = 2*256 + 229
        const int p = tid + (k << 8);
        const float* aI = A + iOff[k];
        const float* aJ = A + jOff[k];
        float* op = outb + p;
#pragma unroll
        for (int cq = 0; cq < 16; ++cq) {
            float4 vi = *(const float4*)(aI + (cq << 2));
            float4 vj = *(const float4*)(aJ + (cq << 2));
            float4 bb = *(const float4*)(sbias + (cq << 2));
            float r0 = vi.x + vj.x + bb.x; r0 = r0 > 0.0f ? r0 : 0.0f;
            float r1 = vi.y + vj.y + bb.y; r1 = r1 > 0.0f ? r1 : 0.0f;
            float r2 = vi.z + vj.z + bb.z; r2 = r2 > 0.0f ? r2 : 0.0f;
            float r3 = vi.w + vj.w + bb.w; r3 = r3 > 0.0f ? r3 : 0.0f;
            __builtin_nontemporal_store(r0, op + (cq * 4 + 0) * NPAIR);
            __builtin_nontemporal_store(r1, op + (cq * 4 + 1) * NPAIR);
            __builtin_nontemporal_store(r2, op + (cq * 4 + 2) * NPAIR);
            __builtin_nontemporal_store(r3, op + (cq * 4 + 3) * NPAIR);
        }
    }
}

extern "C" void kernel_launch(void* const* d_in, const int* in_sizes, int n_in,
                              void* d_out, int out_size, void* d_ws, size_t ws_size,
                              hipStream_t stream) {
    const float* x    = (const float*)d_in[0];
    const float* W    = (const float*)d_in[1];
    const float* bias = (const float*)d_in[2];
    float* out        = (float*)d_out;

    interconv_fused<<<dim3(BATCH), dim3(256), 0, stream>>>(x, W, bias, out);
}

// Round 3
// 452.028 us; speedup vs baseline: 1.0847x; 1.0847x over previous
//
#include <hip/hip_runtime.h>

// InterConv: B=2048, F=39, E=64, C=64, P = F*(F-1)/2 = 741
// out[b*(C*P) + c*P + p] = relu( x[b,ii[p]]·Wi[c] + x[b,jj[p]]·Wj[c] + bias[c] )
//
// Two-kernel design (R3):
//  k1: A[b,f,cw] = x[b,f,:] . [Wi|Wj][:,cw]  -> d_ws (79872 x 128 fp32, 40.9 MB)
//      32 rows/block, W staged in LDS, 4x4 register tiles, float4 stores.
//  k2: block = batch. Stage A-slice [39][128] into LDS stride 129 (odd ->
//      conflict-free gathers), then gather+bias+relu with coalesced b32 stores.
//      LDS ~20.4 KB -> 7 blocks/CU, 28 waves/CU: HBM-write-bound.
// Fallback: proven fused single kernel if ws_size too small.

#define BATCH 2048
#define FDIM  39
#define EDIM  64
#define CDIM  64
#define NPAIR 741
#define CP    (CDIM * NPAIR)     // 47424
#define NROWS (BATCH * FDIM)     // 79872
#define WSTR  132                // W LDS stride (16B-aligned float4 rows)
#define ASTR2 129                // k2 A-slice LDS stride (odd -> bank-friendly)
#define AWSBYTES ((size_t)NROWS * 128 * 4)   // 40894464

// ---------------- kernel 1: row-panel GEMM ----------------
__global__ __launch_bounds__(256) void interconv_gemm(
    const float* __restrict__ x,    // [NROWS, 64] (rows = b*39+f)
    const float* __restrict__ Wg,   // [C,1,2,E] flat: c*128 + wh*64 + e
    float* __restrict__ Ag)         // [NROWS, 128], cw = wh*64 + c
{
    __shared__ float xL[32 * EDIM];      // 8 KB, [r][e] stride 64
    __shared__ float Wl[EDIM * WSTR];    // 33.8 KB, [e][cw]

    const int tid = threadIdx.x;
    const size_t rowBase = (size_t)blockIdx.x * 32;
    const float* xg = x + rowBase * EDIM;

    // stage x rows (contiguous copy): 2048 floats = 512 float4
    for (int q = tid; q < 512; q += 256)
        ((float4*)xL)[q] = ((const float4*)xg)[q];
    // stage W transposed to [e][cw]
    for (int q = tid; q < 2048; q += 256) {
        float4 v = ((const float4*)Wg)[q];
        int flat = q << 2;
        int c   = flat >> 7;
        int rem = flat & 127;
        int wh  = rem >> 6;
        int e0  = rem & 63;
        int cw  = (wh << 6) | c;
        Wl[(e0 + 0) * WSTR + cw] = v.x;
        Wl[(e0 + 1) * WSTR + cw] = v.y;
        Wl[(e0 + 2) * WSTR + cw] = v.z;
        Wl[(e0 + 3) * WSTR + cw] = v.w;
    }
    __syncthreads();

    const int cg  = tid & 31;    // 32 col-groups
    const int rg  = tid >> 5;    // 8 row-groups
    const int cw0 = cg << 2;
    const int r0  = rg << 2;

    float acc[4][4];
#pragma unroll
    for (int a = 0; a < 4; ++a)
#pragma unroll
        for (int q = 0; q < 4; ++q) acc[a][q] = 0.0f;

#pragma unroll 4
    for (int e = 0; e < EDIM; ++e) {
        float4 wv = *(const float4*)(Wl + e * WSTR + cw0);
        float xv[4];
#pragma unroll
        for (int a = 0; a < 4; ++a) xv[a] = xL[(r0 + a) * EDIM + e];
#pragma unroll
        for (int a = 0; a < 4; ++a) {
            acc[a][0] = fmaf(xv[a], wv.x, acc[a][0]);
            acc[a][1] = fmaf(xv[a], wv.y, acc[a][1]);
            acc[a][2] = fmaf(xv[a], wv.z, acc[a][2]);
            acc[a][3] = fmaf(xv[a], wv.w, acc[a][3]);
        }
    }

    float* Aout = Ag + (rowBase + r0) * 128 + cw0;
#pragma unroll
    for (int a = 0; a < 4; ++a)
        *(float4*)(Aout + a * 128) = make_float4(acc[a][0], acc[a][1], acc[a][2], acc[a][3]);
}

// ---------------- kernel 2: gather + bias + relu ----------------
__global__ __launch_bounds__(256) void interconv_gather(
    const float* __restrict__ Ag,    // [NROWS, 128]
    const float* __restrict__ bias,  // [C]
    float* __restrict__ out)         // [B, C*P], layout c*P + p
{
    __shared__ float As[FDIM * ASTR2];   // 5031 floats = 20.1 KB
    __shared__ float sbias[CDIM];

    const int tid = threadIdx.x;
    const int b   = blockIdx.x;
    const float* Ab = Ag + (size_t)b * (FDIM * 128);

    // stage A-slice: coalesced global b32 reads, conflict-free LDS writes
    for (int q = tid; q < FDIM * 128; q += 256)
        As[(q >> 7) * ASTR2 + (q & 127)] = Ab[q];
    if (tid < CDIM) sbias[tid] = bias[tid];
    __syncthreads();

    // decode this thread's 3 pair slots into LDS offsets (registers)
    int iB[3], jB[3];
#pragma unroll
    for (int k = 0; k < 3; ++k) {
        int p = tid + (k << 8);
        if (p >= NPAIR) p = 0;
        int i = (int)floorf((77.0f - sqrtf(5929.0f - 8.0f * (float)p)) * 0.5f);
        i = i < 0 ? 0 : (i > FDIM - 2 ? FDIM - 2 : i);
        while ((i + 1) * (77 - (i + 1)) / 2 <= p) ++i;
        while (i * (77 - i) / 2 > p) --i;
        int j = p - i * (77 - i) / 2 + i + 1;
        iB[k] = i * ASTR2;          // Wi-part at [i][c]
        jB[k] = j * ASTR2 + CDIM;   // Wj-part at [j][64+c]
    }

    float* outb = out + (size_t)b * CP;
    const bool full3 = (tid < NPAIR - 512);   // 741 = 2*256 + 229

#pragma unroll 4
    for (int c = 0; c < CDIM; ++c) {
        const float bc = sbias[c];
        float v0 = As[iB[0] + c] + As[jB[0] + c] + bc;
        float v1 = As[iB[1] + c] + As[jB[1] + c] + bc;
        float v2 = As[iB[2] + c] + As[jB[2] + c] + bc;
        float* oc = outb + c * NPAIR + tid;
        oc[0]   = v0 > 0.0f ? v0 : 0.0f;
        oc[256] = v1 > 0.0f ? v1 : 0.0f;
        if (full3) oc[512] = v2 > 0.0f ? v2 : 0.0f;
    }
}

// ---------------- fallback: proven fused kernel (R1) ----------------
#define XSTR  40
#define ASTRF 41

__global__ __launch_bounds__(256) void interconv_fused(
    const float* __restrict__ x,
    const float* __restrict__ Wg,
    const float* __restrict__ bias,
    float* __restrict__ out)
{
    __shared__ float smem[EDIM * XSTR + EDIM * WSTR];
    __shared__ int   tab[NPAIR];
    __shared__ float sbias[CDIM];

    float* xT = smem;
    float* Wl = smem + EDIM * XSTR;
    float* A  = smem;

    const int tid = threadIdx.x;
    const int b   = blockIdx.x;
    const float* xg = x + (size_t)b * (FDIM * EDIM);

    for (int q = tid; q < (FDIM * EDIM) / 4; q += 256) {
        float4 v = ((const float4*)xg)[q];
        int flat = q << 2;
        int f  = flat >> 6;
        int e0 = flat & 63;
        xT[(e0 + 0) * XSTR + f] = v.x;
        xT[(e0 + 1) * XSTR + f] = v.y;
        xT[(e0 + 2) * XSTR + f] = v.z;
        xT[(e0 + 3) * XSTR + f] = v.w;
    }
    for (int q = tid; q < (CDIM * 2 * EDIM) / 4; q += 256) {
        float4 v = ((const float4*)Wg)[q];
        int flat = q << 2;
        int c   = flat >> 7;
        int rem = flat & 127;
        int wh  = rem >> 6;
        int e0  = rem & 63;
        int cw  = (wh << 6) | c;
        Wl[(e0 + 0) * WSTR + cw] = v.x;
        Wl[(e0 + 1) * WSTR + cw] = v.y;
        Wl[(e0 + 2) * WSTR + cw] = v.z;
        Wl[(e0 + 3) * WSTR + cw] = v.w;
    }
    for (int idx = tid; idx < NPAIR; idx += 256) {
        int i = (int)floorf((77.0f - sqrtf(5929.0f - 8.0f * (float)idx)) * 0.5f);
        i = i < 0 ? 0 : (i > FDIM - 2 ? FDIM - 2 : i);
        while ((i + 1) * (77 - (i + 1)) / 2 <= idx) ++i;
        while (i * (77 - i) / 2 > idx) --i;
        int j = idx - i * (77 - i) / 2 + i + 1;
        tab[idx] = i | (j << 8);
    }
    if (tid < CDIM) sbias[tid] = bias[tid];
    __syncthreads();

    const int ft  = tid >> 5;
    const int ct  = tid & 31;
    const int f0  = ft * 5;
    const int cw0 = ct << 2;

    float acc[5][4];
#pragma unroll
    for (int a = 0; a < 5; ++a)
#pragma unroll
        for (int q = 0; q < 4; ++q) acc[a][q] = 0.0f;

#pragma unroll 4
    for (int e = 0; e < EDIM; ++e) {
        float4 wv = *(const float4*)(Wl + e * WSTR + cw0);
        float xv[5];
#pragma unroll
        for (int a = 0; a < 5; ++a) xv[a] = xT[e * XSTR + f0 + a];
#pragma unroll
        for (int a = 0; a < 5; ++a) {
            acc[a][0] = fmaf(xv[a], wv.x, acc[a][0]);
            acc[a][1] = fmaf(xv[a], wv.y, acc[a][1]);
            acc[a][2] = fmaf(xv[a], wv.z, acc[a][2]);
            acc[a][3] = fmaf(xv[a], wv.w, acc[a][3]);
        }
    }
    __syncthreads();

#pragma unroll
    for (int a = 0; a < 5; ++a)
#pragma unroll
        for (int q = 0; q < 4; ++q)
            A[(cw0 + q) * ASTRF + (f0 + a)] = acc[a][q];
    __syncthreads();

    float* outb = out + (size_t)b * CP;
    for (int c = 0; c < CDIM; ++c) {
        const float bc = sbias[c];
        const float* rI = A + c * ASTRF;
        const float* rJ = A + (64 + c) * ASTRF;
        float* oc = outb + c * NPAIR;
        for (int p = tid; p < NPAIR; p += 256) {
            int t = tab[p];
            float v = rI[t & 0xff] + rJ[t >> 8] + bc;
            oc[p] = v > 0.0f ? v : 0.0f;
        }
    }
}

extern "C" void kernel_launch(void* const* d_in, const int* in_sizes, int n_in,
                              void* d_out, int out_size, void* d_ws, size_t ws_size,
                              hipStream_t stream) {
    const float* x    = (const float*)d_in[0];
    const float* W    = (const float*)d_in[1];
    const float* bias = (const float*)d_in[2];
    float* out        = (float*)d_out;

    if (ws_size >= AWSBYTES) {
        float* Ag = (float*)d_ws;
        interconv_gemm<<<dim3(NROWS / 32), dim3(256), 0, stream>>>(x, W, Ag);
        interconv_gather<<<dim3(BATCH), dim3(256), 0, stream>>>(Ag, bias, out);
    } else {
        interconv_fused<<<dim3(BATCH), dim3(256), 0, stream>>>(x, W, bias, out);
    }
}